// Round 20
// baseline (414.631 us; speedup 1.0000x reference)
//
#include <hip/hip_runtime.h>
#include <hip/hip_cooperative_groups.h>
#include <hip/hip_fp16.h>
#include <cmath>

#define N_NODES 50000
#define NPAD 50016           // per-XCD packed stride; index N_NODES = dummy slot for OOB lanes
#define DIM 64
#define E_EDGES 800000
#define FIX32 65536.0f       // 2^16 fixed-point scale for deg (24-bit field, max 256)
#define NB_A 98              // score/sort blocks: 98 * 512 = 50176 >= 50000
#define NB_EDGE 391          // edge blocks: 391*512*4 = 800768 >= 800000 (4 edges/thread)
#define ESTRIDE (NB_EDGE * 512)
#define NRUNS 98             // sorted runs of 64 entering phase B
#define NXCD 8               // MI355X: 8 XCDs, per-XCD L2 (non-coherent)
#define BUCKET8 24           // per-(xcd,node) bucket capacity; deg ~Poisson(16) total
#define XW_BLOCKS 782        // ceil(50000 / 64) xw tiles
#define NB_TAIL 512          // cooperative tail grid: 512 blocks x 256 thr (coop-safe)

// ATOMIC WALL LEDGER (r10-r35): shared+sc1=53us; per-XCD sc0=50us; 4x-outstanding=48.7us;
// 32B-padded slots=48-50us FLAT -> same-line serialization REFUTED. Wall = per-op TCC
// service rate / ren8 scattered-store path. Remaining lever: LDS-binning rewrite —
// parked. THIS KERNEL (r25, resubmitted r26-r35 after acquisition-stage infra
// timeouts — failures are content-independent): totals invariant at ~204us while
// edge=49us; ~155us unattributed (top-5 saturated by edge replays). Fuse entire tail
// into ONE cooperative kernel: attributes the budget + removes 3 launch boundaries.
// Edge kernel = exact r6-measured config as control.

// XCD id of the executing wave (HW-verified on gfx950: s_getreg HW_REG_XCC_ID, m09)
__device__ __forceinline__ int xcc_id() {
    int x;
    asm volatile("s_getreg_b32 %0, hwreg(HW_REG_XCC_ID)" : "=s"(x));
    return x & 7;
}

// ======== wave-register bitonic helpers (comparator: val desc, idx asc) ========
__device__ __forceinline__ void wave_sort64(float& v, int& idx, int lane) {
    #pragma unroll
    for (int k = 2; k <= 64; k <<= 1) {
        #pragma unroll
        for (int j = k >> 1; j > 0; j >>= 1) {
            float ov = __shfl_xor(v, j);
            int   oi = __shfl_xor(idx, j);
            bool lower = ((lane & j) == 0);
            bool up    = ((lane & k) == 0);
            bool mine_prec = (v > ov) || (v == ov && idx < oi);
            bool keep = up ? (lower == mine_prec) : (lower != mine_prec);
            if (!keep) { v = ov; idx = oi; }
        }
    }
}

// A (desc, in regs) merged with B (bv/bi must hold B[63-lane]); result: top-64 desc
__device__ __forceinline__ void wave_merge_top64(float& v, int& idx,
                                                 float bv, int bi, int lane) {
    bool a_prec = (v > bv) || (v == bv && idx < bi);
    if (!a_prec) { v = bv; idx = bi; }
    #pragma unroll
    for (int j = 32; j > 0; j >>= 1) {
        float ov = __shfl_xor(v, j);
        int   oi = __shfl_xor(idx, j);
        bool lower = ((lane & j) == 0);
        bool mine_prec = (v > ov) || (v == ov && idx < oi);
        bool keep = (lower == mine_prec);   // up = true (full-width merge)
        if (!keep) { v = ov; idx = oi; }
    }
}

// ------ fused: score + top-k phase A (blocks<98) + batched edge pass (all blocks) ------
// Exact r6-measured config (control): 4 edges/thread, 4 L2-local RMWs in flight.
__global__ __launch_bounds__(512) void score_topk_edge_kernel(
    const float* __restrict__ x, const float* __restrict__ p,
    float* __restrict__ cand_val, int* __restrict__ cand_idx,
    const int* __restrict__ ei, const float* __restrict__ ew,
    unsigned int* __restrict__ packed8, unsigned int* __restrict__ ren8) {
    __shared__ float sv[512];
    __shared__ int   si[512];
    int t = threadIdx.x, lane = t & 63, wvid = t >> 6;
    if (blockIdx.x < NB_A) {
        int g = blockIdx.x * 512 + t;
        float v; int idx;
        if (g < N_NODES) {
            const float4* x4 = (const float4*)(x + (size_t)g * DIM);
            const float4* p4 = (const float4*)p;
            float dot = 0.f, pn = 0.f;
            #pragma unroll
            for (int k = 0; k < 16; k++) {
                float4 xv = x4[k], pv = p4[k];
                dot += xv.x * pv.x + xv.y * pv.y + xv.z * pv.z + xv.w * pv.w;
                pn  += pv.x * pv.x + pv.y * pv.y + pv.z * pv.z + pv.w * pv.w;
            }
            v = dot / sqrtf(pn);
            idx = g;
        } else { v = -INFINITY; idx = 0x7fffffff; }
        wave_sort64(v, idx, lane);
        sv[t] = v; si[t] = idx;
        __syncthreads();
        if (wvid == 0) {
            #pragma unroll
            for (int r = 1; r < 8; r++)
                wave_merge_top64(v, idx, sv[r * 64 + 63 - lane], si[r * 64 + 63 - lane], lane);
            cand_val[blockIdx.x * 64 + lane] = v;
            cand_idx[blockIdx.x * 64 + lane] = idx;
        }
    }
    // ---- batched edge pass: 4 edges/thread, 4 L2-local RMWs in flight ----
    int xcc = xcc_id();
    unsigned int* mypk  = packed8 + (size_t)xcc * NPAD;
    unsigned int* myren = ren8 + (size_t)xcc * N_NODES * BUCKET8;
    int e0 = blockIdx.x * 512 + t;       // 0 .. ESTRIDE-1
    int   rr[4]; int cc[4]; float wwv[4]; bool valid[4];
    #pragma unroll
    for (int k = 0; k < 4; k++) {
        int e = e0 + k * ESTRIDE;
        bool vld = (e < E_EDGES);
        int ie = vld ? e : 0;
        rr[k]  = ei[ie];
        cc[k]  = vld ? ei[E_EDGES + ie] : N_NODES;   // dummy slot for OOB
        wwv[k] = ew[ie];
        valid[k] = vld;
    }
    unsigned int q[4];
    unsigned int* ap[4];
    #pragma unroll
    for (int k = 0; k < 4; k++) {
        q[k] = valid[k] ? ((1u << 24) | (unsigned int)(wwv[k] * FIX32)) : 0u;
        ap[k] = &mypk[cc[k]];
    }
    unsigned int o0, o1, o2, o3;
    asm volatile(
        "global_atomic_add %0, %4, %8, off sc0\n\t"
        "global_atomic_add %1, %5, %9, off sc0\n\t"
        "global_atomic_add %2, %6, %10, off sc0\n\t"
        "global_atomic_add %3, %7, %11, off sc0\n\t"
        "s_waitcnt vmcnt(0)"
        : "=&v"(o0), "=&v"(o1), "=&v"(o2), "=&v"(o3)
        : "v"(ap[0]), "v"(ap[1]), "v"(ap[2]), "v"(ap[3]),
          "v"(q[0]), "v"(q[1]), "v"(q[2]), "v"(q[3])
        : "memory");
    unsigned int oo[4] = {o0, o1, o2, o3};
    #pragma unroll
    for (int k = 0; k < 4; k++) {
        unsigned int pos = oo[k] >> 24;
        if (valid[k] && pos < BUCKET8) {
            __half hw = __float2half(wwv[k]);
            unsigned int rec = ((unsigned int)__half_as_ushort(hw) << 16) | (unsigned int)rr[k];
            myren[(size_t)cc[k] * BUCKET8 + pos] = rec;
        }
    }
}

// ============ fused tail: topk-B -> GRU -> xw -> gather+head (cooperative) ============
// 512 blocks x 256 thr; 33KB LDS -> 4 blocks/CU capacity, 512 co-resident guaranteed.
__global__ __launch_bounds__(256) void fused_tail_kernel(
    const float* __restrict__ cand_val, const int* __restrict__ cand_idx,
    const float* __restrict__ x, float* __restrict__ x_tilde,
    const float* __restrict__ initW, const float* __restrict__ Wih,
    const float* __restrict__ Whh, const float* __restrict__ bih,
    const float* __restrict__ bhh, float* __restrict__ W,
    const unsigned int* __restrict__ packed8, const unsigned int* __restrict__ ren8,
    __half* __restrict__ xwh, const float* __restrict__ linW,
    const float* __restrict__ linb, float* __restrict__ out) {
    namespace cg = cooperative_groups;
    cg::grid_group grid = cg::this_grid();
    __shared__ float smem[8256];      // 33 KB, aliased per phase
    int t = threadIdx.x, lane = t & 63, wv = t >> 6;
    int bx = blockIdx.x;

    // ---- phase T: merge 98 runs -> top-64, tanh, x_tilde (block 0 only) ----
    if (bx == 0) {
        float* rsv  = smem;                    // [4*64]
        int*   rsi  = (int*)(smem + 256);      // [4*64]
        float* tval = smem + 512;              // [64]
        int*   perm = (int*)(smem + 576);      // [64]
        float v = cand_val[wv * 64 + lane];
        int idx   = cand_idx[wv * 64 + lane];
        for (int r = wv + 4; r < NRUNS; r += 4)
            wave_merge_top64(v, idx, cand_val[r * 64 + 63 - lane],
                             cand_idx[r * 64 + 63 - lane], lane);
        rsv[wv * 64 + lane] = v; rsi[wv * 64 + lane] = idx;
        __syncthreads();
        if (wv == 0) {
            #pragma unroll
            for (int r = 1; r < 4; r++)
                wave_merge_top64(v, idx, rsv[r * 64 + 63 - lane],
                                 rsi[r * 64 + 63 - lane], lane);
            tval[lane] = tanhf(v);
            perm[lane] = idx;
        }
        __syncthreads();
        for (int i = t; i < 4096; i += 256) {
            int j = i >> 6, kk = i & 63;
            x_tilde[i] = x[(size_t)perm[j] * DIM + kk] * tval[j];
        }
    }
    grid.sync();

    // ---- phase G: GRU step (blocks 0..15, 4 rows each; identical math) ----
    if (bx < 16) {
        float* xrow_s = smem;        // [256]
        float* hrow_s = smem + 256;  // [256]
        int i = bx * 4 + wv;         // row 0..63
        int j = lane;
        int li = wv * 64 + j;
        xrow_s[li] = x_tilde[i * 64 + j];
        hrow_s[li] = initW[i * 64 + j];
        __syncthreads();
        int lb = wv * 64;
        float gi_r = bih[j], gi_z = bih[j + 64], gi_n = bih[j + 128];
        float gh_r = bhh[j], gh_z = bhh[j + 64], gh_n = bhh[j + 128];
        for (int k = 0; k < 64; k++) {
            float xv = xrow_s[lb + k], hv = hrow_s[lb + k];
            gi_r += xv * Wih[j * 64 + k];
            gi_z += xv * Wih[(j + 64) * 64 + k];
            gi_n += xv * Wih[(j + 128) * 64 + k];
            gh_r += hv * Whh[j * 64 + k];
            gh_z += hv * Whh[(j + 64) * 64 + k];
            gh_n += hv * Whh[(j + 128) * 64 + k];
        }
        float r_ = 1.f / (1.f + expf(-(gi_r + gh_r)));
        float z_ = 1.f / (1.f + expf(-(gi_z + gh_z)));
        float nn = tanhf(gi_n + r_ * gh_n);
        W[i * 64 + j] = (1.f - z_) * nn + z_ * hrow_s[lb + j];
    }
    grid.sync();

    // ---- phase X: xw = dinv[r]*(x @ W) -> fp16, grid-stride over 782 tiles ----
    {
        float* Wl     = smem;          // [4096]
        float* Xl     = smem + 4096;   // [4096]
        float* dinv_s = smem + 8192;   // [64]
        for (int i = t; i < 4096; i += 256) Wl[i] = W[i];
        for (int tile = bx; tile < XW_BLOCKS; tile += NB_TAIL) {
            __syncthreads();           // Wl ready / prev tile compute done
            int r0 = tile * 64;
            if (t < 64) {
                int r = r0 + t;
                unsigned int s = 0;
                if (r < N_NODES) {
                    #pragma unroll
                    for (int xx = 0; xx < NXCD; xx++)
                        s += packed8[(size_t)xx * NPAD + r] & 0xFFFFFFu;
                }
                dinv_s[t] = rsqrtf((float)s * (1.0f / FIX32) + 1.0f);
            }
            for (int i = t; i < 4096; i += 256) {
                int r = r0 + (i >> 6);
                Xl[i] = (r < N_NODES) ? x[r0 * 64 + i] : 0.f;
            }
            __syncthreads();
            int j = t & 63, ty = t >> 6;
            float acc[16];
            #pragma unroll
            for (int rr = 0; rr < 16; rr++) acc[rr] = 0.f;
            for (int k = 0; k < 64; k++) {
                float wvv = Wl[k * 64 + j];
                #pragma unroll
                for (int rr = 0; rr < 16; rr++)
                    acc[rr] += Xl[(ty * 16 + rr) * 64 + k] * wvv;
            }
            #pragma unroll
            for (int rr = 0; rr < 16; rr++) {
                int r = r0 + ty * 16 + rr;
                if (r < N_NODES)
                    xwh[r * DIM + j] = __float2half(acc[rr] * dinv_s[ty * 16 + rr]);
            }
        }
    }
    grid.sync();

    // ---- phase H: gather + head, wave-strided over all 50000 nodes ----
    {
        const float4* xwh4 = (const float4*)xwh;
        int gw = bx * 4 + wv;            // global wave id, 0..2047
        int c8 = lane & 7;
        int slot = lane >> 3;
        float lw[8];
        #pragma unroll
        for (int q = 0; q < 8; q++) lw[q] = linW[c8 * 8 + q];
        float lb0 = linb[0];
        for (int n = gw; n < N_NODES; n += NB_TAIL * 4) {
            int xsel = -1, xslot = 0, pref = 0;
            unsigned int wfix = 0;
            #pragma unroll
            for (int xx = 0; xx < NXCD; xx++) {
                unsigned int pkx = packed8[(size_t)xx * NPAD + n];   // broadcast load
                int cx = min((int)(pkx >> 24), BUCKET8);
                wfix += pkx & 0xFFFFFFu;
                if (lane >= pref && lane < pref + cx) { xsel = xx; xslot = lane - pref; }
                pref += cx;
            }
            int cnt = min(pref, 64);
            float di = rsqrtf((float)wfix * (1.0f / FIX32) + 1.0f);
            float acc[8];
            #pragma unroll
            for (int q = 0; q < 8; q++) acc[q] = 0.f;
            if (slot == 0) {
                float4 hv = xwh4[n * 8 + c8];
                const __half2* h2 = reinterpret_cast<const __half2*>(&hv);
                #pragma unroll
                for (int q = 0; q < 4; q++) {
                    float2 f = __half22float2(h2[q]);
                    acc[2 * q]     = f.x;
                    acc[2 * q + 1] = f.y;
                }
            }
            int rv = 0; float wvd = 0.f;
            if (xsel >= 0 && lane < cnt) {
                unsigned int rec = ren8[((size_t)xsel * N_NODES + n) * BUCKET8 + xslot];
                rv = (int)(rec & 0xFFFFu);
                __half_raw hr; hr.x = (unsigned short)(rec >> 16);
                wvd = __half2float(__half(hr));
            }
            int G = (cnt + 7) >> 3;
            int g = 0;
            for (; g + 2 <= G; g += 2) {      // 16 independent gathers in flight
                int src0 = g * 8 + slot, src1 = src0 + 8;
                int   ra = __shfl(rv, src0);  float wa = __shfl(wvd, src0);
                int   rb = __shfl(rv, src1);  float wb = __shfl(wvd, src1);
                float4 ha = xwh4[ra * 8 + c8];
                float4 hb = xwh4[rb * 8 + c8];
                const __half2* h2a = reinterpret_cast<const __half2*>(&ha);
                const __half2* h2b = reinterpret_cast<const __half2*>(&hb);
                #pragma unroll
                for (int q = 0; q < 4; q++) {
                    float2 fa = __half22float2(h2a[q]);
                    float2 fb = __half22float2(h2b[q]);
                    acc[2 * q]     += wa * fa.x + wb * fb.x;
                    acc[2 * q + 1] += wa * fa.y + wb * fb.y;
                }
            }
            if (g < G) {
                int src = g * 8 + slot;
                int r = __shfl(rv, src);      // inactive slots: wvd=0 -> no-op FMA
                float ww = __shfl(wvd, src);
                float4 hv = xwh4[r * 8 + c8];
                const __half2* h2 = reinterpret_cast<const __half2*>(&hv);
                #pragma unroll
                for (int q = 0; q < 4; q++) {
                    float2 f = __half22float2(h2[q]);
                    acc[2 * q]     += ww * f.x;
                    acc[2 * q + 1] += ww * f.y;
                }
            }
            #pragma unroll
            for (int q = 0; q < 8; q++) {
                acc[q] += __shfl_xor(acc[q], 8);
                acc[q] += __shfl_xor(acc[q], 16);
                acc[q] += __shfl_xor(acc[q], 32);
            }
            float pv = 0.f;
            #pragma unroll
            for (int q = 0; q < 8; q++)
                pv += fmaxf(di * acc[q], 0.f) * lw[q];
            pv += __shfl_xor(pv, 1); pv += __shfl_xor(pv, 2); pv += __shfl_xor(pv, 4);
            if (lane == 0) out[n] = pv + lb0;
        }
    }
}

extern "C" void kernel_launch(void* const* d_in, const int* in_sizes, int n_in,
                              void* d_out, int out_size, void* d_ws, size_t ws_size,
                              hipStream_t stream) {
    const float* x     = (const float*)d_in[0];
    const int*   ei    = (const int*)d_in[1];
    const float* ew    = (const float*)d_in[2];
    const float* p     = (const float*)d_in[3];
    const float* initW = (const float*)d_in[4];
    const float* Wih   = (const float*)d_in[5];
    const float* Whh   = (const float*)d_in[6];
    const float* bih   = (const float*)d_in[7];
    const float* bhh   = (const float*)d_in[8];
    const float* linW  = (const float*)d_in[9];
    const float* linb  = (const float*)d_in[10];
    float* out = (float*)d_out;

    char* w = (char*)d_ws;
    unsigned int* packed8 = (unsigned int*)w; w += 4ull * NXCD * NPAD;              // 1.6 MB
    unsigned int* ren8 = (unsigned int*)w;    w += 4ull * NXCD * N_NODES * BUCKET8; // 38.4 MB
    __half* xwh    = (__half*)w;   w += 2ull * (size_t)N_NODES * DIM;               // 6.4 MB
    float* cand_val= (float*)w;    w += 4ull * 8192;
    int*   cand_idx= (int*)w;      w += 4ull * 8192;
    float* x_tilde = (float*)w;    w += 4ull * 4096;
    float* W       = (float*)w;    w += 4ull * 4096;

    // zero the 8 per-XCD counter copies (capture-legal memset node)
    hipMemsetAsync(packed8, 0, 4ull * NXCD * NPAD, stream);
    score_topk_edge_kernel<<<NB_EDGE, 512, 0, stream>>>(
        x, p, cand_val, cand_idx, ei, ew, packed8, ren8);
    void* args[] = {
        (void*)&cand_val, (void*)&cand_idx, (void*)&x, (void*)&x_tilde,
        (void*)&initW, (void*)&Wih, (void*)&Whh, (void*)&bih, (void*)&bhh,
        (void*)&W, (void*)&packed8, (void*)&ren8, (void*)&xwh,
        (void*)&linW, (void*)&linb, (void*)&out };
    hipLaunchCooperativeKernel((void*)fused_tail_kernel, dim3(NB_TAIL), dim3(256),
                               args, 0, stream);
}

// Round 21
// 357.116 us; speedup vs baseline: 1.1611x; 1.1611x over previous
//
#include <hip/hip_runtime.h>
#include <hip/hip_fp16.h>
#include <cmath>

#define N_NODES 50000
#define NPAD 50016           // per-XCD packed stride; index N_NODES = dummy slot for OOB lanes
#define DIM 64
#define E_EDGES 800000
#define FIX32 65536.0f       // 2^16 fixed-point scale for deg (24-bit field, max 256)
#define NB_A 98              // score/sort blocks: 98 * 512 = 50176 >= 50000
#define NB_EDGE 391          // edge blocks: 391*512*4 = 800768 >= 800000 (4 edges/thread)
#define ESTRIDE (NB_EDGE * 512)
#define NRUNS 98             // sorted runs of 64 entering phase B
#define NXCD 8               // MI355X: 8 XCDs, per-XCD L2 (non-coherent)
#define BUCKET8 24           // per-(xcd,node) bucket capacity; deg ~Poisson(16) total
#define XW_BLOCKS 782        // ceil(50000 / 64)

// LEDGER (r10-r36). Edge atomic wall: shared+sc1=53us; per-XCD sc0=50us;
// 4x-outstanding=48.7us; 32B-padded slots=flat -> same-line serialization REFUTED;
// wall = per-op TCC service / ren8 scattered-store path. r20 MEASURED the coop-fused
// tail: 267us at 23% occupancy, VALU 10% -> TLP-STARVED (coop grid 2048 waves vs
// 50000 for standalone gather). FUSION REVERTED. Budget model from r20: fixed
// harness overhead ~95us (invariant to dispatch count) + edge ~49 + tail ~55.
// r21 (this): r9 multi-kernel structure restored; topk-B+GRU fused into ONE
// single-block kernel (x_tilde stays in LDS; -1 dispatch, -1 global roundtrip).
// Next lever: edge-pass binning rewrite (edge is the largest controllable kernel).

// XCD id of the executing wave (HW-verified on gfx950: s_getreg HW_REG_XCC_ID, m09)
__device__ __forceinline__ int xcc_id() {
    int x;
    asm volatile("s_getreg_b32 %0, hwreg(HW_REG_XCC_ID)" : "=s"(x));
    return x & 7;
}

// ======== wave-register bitonic helpers (comparator: val desc, idx asc) ========
__device__ __forceinline__ void wave_sort64(float& v, int& idx, int lane) {
    #pragma unroll
    for (int k = 2; k <= 64; k <<= 1) {
        #pragma unroll
        for (int j = k >> 1; j > 0; j >>= 1) {
            float ov = __shfl_xor(v, j);
            int   oi = __shfl_xor(idx, j);
            bool lower = ((lane & j) == 0);
            bool up    = ((lane & k) == 0);
            bool mine_prec = (v > ov) || (v == ov && idx < oi);
            bool keep = up ? (lower == mine_prec) : (lower != mine_prec);
            if (!keep) { v = ov; idx = oi; }
        }
    }
}

// A (desc, in regs) merged with B (bv/bi must hold B[63-lane]); result: top-64 desc
__device__ __forceinline__ void wave_merge_top64(float& v, int& idx,
                                                 float bv, int bi, int lane) {
    bool a_prec = (v > bv) || (v == bv && idx < bi);
    if (!a_prec) { v = bv; idx = bi; }
    #pragma unroll
    for (int j = 32; j > 0; j >>= 1) {
        float ov = __shfl_xor(v, j);
        int   oi = __shfl_xor(idx, j);
        bool lower = ((lane & j) == 0);
        bool mine_prec = (v > ov) || (v == ov && idx < oi);
        bool keep = (lower == mine_prec);   // up = true (full-width merge)
        if (!keep) { v = ov; idx = oi; }
    }
}

// ------ fused: score + top-k phase A (blocks<98) + batched edge pass (all blocks) ------
// Exact r6-measured config: 4 edges/thread, 4 L2-local RMWs in flight.
__global__ __launch_bounds__(512) void score_topk_edge_kernel(
    const float* __restrict__ x, const float* __restrict__ p,
    float* __restrict__ cand_val, int* __restrict__ cand_idx,
    const int* __restrict__ ei, const float* __restrict__ ew,
    unsigned int* __restrict__ packed8, unsigned int* __restrict__ ren8) {
    __shared__ float sv[512];
    __shared__ int   si[512];
    int t = threadIdx.x, lane = t & 63, wvid = t >> 6;
    if (blockIdx.x < NB_A) {
        int g = blockIdx.x * 512 + t;
        float v; int idx;
        if (g < N_NODES) {
            const float4* x4 = (const float4*)(x + (size_t)g * DIM);
            const float4* p4 = (const float4*)p;
            float dot = 0.f, pn = 0.f;
            #pragma unroll
            for (int k = 0; k < 16; k++) {
                float4 xv = x4[k], pv = p4[k];
                dot += xv.x * pv.x + xv.y * pv.y + xv.z * pv.z + xv.w * pv.w;
                pn  += pv.x * pv.x + pv.y * pv.y + pv.z * pv.z + pv.w * pv.w;
            }
            v = dot / sqrtf(pn);
            idx = g;
        } else { v = -INFINITY; idx = 0x7fffffff; }
        wave_sort64(v, idx, lane);
        sv[t] = v; si[t] = idx;
        __syncthreads();
        if (wvid == 0) {
            #pragma unroll
            for (int r = 1; r < 8; r++)
                wave_merge_top64(v, idx, sv[r * 64 + 63 - lane], si[r * 64 + 63 - lane], lane);
            cand_val[blockIdx.x * 64 + lane] = v;
            cand_idx[blockIdx.x * 64 + lane] = idx;
        }
    }
    // ---- batched edge pass: 4 edges/thread, 4 L2-local RMWs in flight ----
    int xcc = xcc_id();
    unsigned int* mypk  = packed8 + (size_t)xcc * NPAD;
    unsigned int* myren = ren8 + (size_t)xcc * N_NODES * BUCKET8;
    int e0 = blockIdx.x * 512 + t;       // 0 .. ESTRIDE-1
    int   rr[4]; int cc[4]; float wwv[4]; bool valid[4];
    #pragma unroll
    for (int k = 0; k < 4; k++) {
        int e = e0 + k * ESTRIDE;
        bool vld = (e < E_EDGES);
        int ie = vld ? e : 0;
        rr[k]  = ei[ie];
        cc[k]  = vld ? ei[E_EDGES + ie] : N_NODES;   // dummy slot for OOB
        wwv[k] = ew[ie];
        valid[k] = vld;
    }
    unsigned int q[4];
    unsigned int* ap[4];
    #pragma unroll
    for (int k = 0; k < 4; k++) {
        q[k] = valid[k] ? ((1u << 24) | (unsigned int)(wwv[k] * FIX32)) : 0u;
        ap[k] = &mypk[cc[k]];
    }
    unsigned int o0, o1, o2, o3;
    asm volatile(
        "global_atomic_add %0, %4, %8, off sc0\n\t"
        "global_atomic_add %1, %5, %9, off sc0\n\t"
        "global_atomic_add %2, %6, %10, off sc0\n\t"
        "global_atomic_add %3, %7, %11, off sc0\n\t"
        "s_waitcnt vmcnt(0)"
        : "=&v"(o0), "=&v"(o1), "=&v"(o2), "=&v"(o3)
        : "v"(ap[0]), "v"(ap[1]), "v"(ap[2]), "v"(ap[3]),
          "v"(q[0]), "v"(q[1]), "v"(q[2]), "v"(q[3])
        : "memory");
    unsigned int oo[4] = {o0, o1, o2, o3};
    #pragma unroll
    for (int k = 0; k < 4; k++) {
        unsigned int pos = oo[k] >> 24;
        if (valid[k] && pos < BUCKET8) {
            __half hw = __float2half(wwv[k]);
            unsigned int rec = ((unsigned int)__half_as_ushort(hw) << 16) | (unsigned int)rr[k];
            myren[(size_t)cc[k] * BUCKET8 + pos] = rec;
        }
    }
}

// ------- fused top-k phase B + GRU (ONE block x 1024; x_tilde lives in LDS) -------
__global__ __launch_bounds__(1024) void topk_gru_kernel(
    const float* __restrict__ cand_val, const int* __restrict__ cand_idx,
    const float* __restrict__ x, const float* __restrict__ initW,
    const float* __restrict__ Wih, const float* __restrict__ Whh,
    const float* __restrict__ bih, const float* __restrict__ bhh,
    float* __restrict__ Wout) {
    __shared__ float rsv[16 * 64];
    __shared__ int   rsi[16 * 64];
    __shared__ float tval[64];
    __shared__ int   perm[64];
    __shared__ float xt_s[4096];   // x_tilde, LDS-resident (GRU is its only consumer)
    __shared__ float h_s[4096];    // initW
    int t = threadIdx.x, lane = t & 63, wv = t >> 6;
    int r0 = wv * 8;
    float v; int idx;
    if (r0 < NRUNS) { v = cand_val[r0 * 64 + lane]; idx = cand_idx[r0 * 64 + lane]; }
    else            { v = -INFINITY; idx = 0x7fffffff; }
    for (int r = r0 + 1; r < r0 + 8 && r < NRUNS; r++)
        wave_merge_top64(v, idx, cand_val[r * 64 + 63 - lane],
                         cand_idx[r * 64 + 63 - lane], lane);
    rsv[wv * 64 + lane] = v; rsi[wv * 64 + lane] = idx;
    __syncthreads();
    if (wv == 0) {
        v = rsv[lane]; idx = rsi[lane];
        for (int r = 1; r < 16; r++)
            wave_merge_top64(v, idx, rsv[r * 64 + 63 - lane],
                             rsi[r * 64 + 63 - lane], lane);
        tval[lane] = tanhf(v);
        perm[lane] = idx;
    }
    __syncthreads();
    for (int i = t; i < 4096; i += 1024) {
        int j = i >> 6, kk = i & 63;
        xt_s[i] = x[(size_t)perm[j] * DIM + kk] * tval[j];
        h_s[i]  = initW[i];
    }
    __syncthreads();
    // GRU: 4096 outputs over 1024 threads (4 each); identical math to r9 gru_kernel
    #pragma unroll
    for (int p = 0; p < 4; p++) {
        int o = t + p * 1024;
        int i = o >> 6, j = o & 63;
        int lb = i * 64;
        float gi_r = bih[j], gi_z = bih[j + 64], gi_n = bih[j + 128];
        float gh_r = bhh[j], gh_z = bhh[j + 64], gh_n = bhh[j + 128];
        for (int k = 0; k < 64; k++) {
            float xv = xt_s[lb + k], hv = h_s[lb + k];
            gi_r += xv * Wih[j * 64 + k];
            gi_z += xv * Wih[(j + 64) * 64 + k];
            gi_n += xv * Wih[(j + 128) * 64 + k];
            gh_r += hv * Whh[j * 64 + k];
            gh_z += hv * Whh[(j + 64) * 64 + k];
            gh_n += hv * Whh[(j + 128) * 64 + k];
        }
        float r_ = 1.f / (1.f + expf(-(gi_r + gh_r)));
        float z_ = 1.f / (1.f + expf(-(gi_z + gh_z)));
        float nn = tanhf(gi_n + r_ * gh_n);
        Wout[o] = (1.f - z_) * nn + z_ * h_s[lb + j];
    }
}

// ---------------- xw = dinv[r] * (x @ W), output fp16 (exact r9 form) ----------------
__global__ __launch_bounds__(256) void xw_kernel(
    const float* __restrict__ x, const float* __restrict__ W,
    const unsigned int* __restrict__ packed8, __half* __restrict__ xwh) {
    __shared__ float Wl[64 * 64];
    __shared__ float Xl[64 * 64];
    __shared__ float dinv_s[64];
    int t = threadIdx.x;
    int r0 = blockIdx.x * 64;
    if (t < 64) {
        int r = r0 + t;
        unsigned int s = 0;
        if (r < N_NODES) {
            #pragma unroll
            for (int xx = 0; xx < NXCD; xx++)
                s += packed8[(size_t)xx * NPAD + r] & 0xFFFFFFu;
        }
        dinv_s[t] = rsqrtf((float)s * (1.0f / FIX32) + 1.0f);
    }
    for (int i = t; i < 4096; i += 256) Wl[i] = W[i];
    for (int i = t; i < 4096; i += 256) {
        int r = r0 + (i >> 6);
        Xl[i] = (r < N_NODES) ? x[r0 * 64 + i] : 0.f;
    }
    __syncthreads();
    int j = t & 63, ty = t >> 6;
    float acc[16];
    #pragma unroll
    for (int rr = 0; rr < 16; rr++) acc[rr] = 0.f;
    for (int k = 0; k < 64; k++) {
        float wvv = Wl[k * 64 + j];
        #pragma unroll
        for (int rr = 0; rr < 16; rr++)
            acc[rr] += Xl[(ty * 16 + rr) * 64 + k] * wvv;
    }
    #pragma unroll
    for (int rr = 0; rr < 16; rr++) {
        int r = r0 + ty * 16 + rr;
        if (r < N_NODES)
            xwh[r * DIM + j] = __float2half(acc[rr] * dinv_s[ty * 16 + rr]);
    }
}

// ------- gather + fused head: wave per node, full occupancy (exact r9 form) -------
__global__ __launch_bounds__(256) void gather_head_kernel(
    const unsigned int* __restrict__ packed8, const unsigned int* __restrict__ ren8,
    const float4* __restrict__ xwh,   // 8 float4 (= 64 halves) per row
    const float* __restrict__ linW, const float* __restrict__ linb,
    float* __restrict__ out) {
    int gid = blockIdx.x * blockDim.x + threadIdx.x;
    int n = gid >> 6, lane = gid & 63;
    if (n >= N_NODES) return;
    int c8 = lane & 7;        // columns c8*8 .. c8*8+7
    int slot = lane >> 3;     // 8 row-slots per wave
    // per-XCD counts -> lane's (list, slot) assignment + total weighted degree
    int xsel = -1, xslot = 0, pref = 0;
    unsigned int wfix = 0;
    #pragma unroll
    for (int xx = 0; xx < NXCD; xx++) {
        unsigned int pkx = packed8[(size_t)xx * NPAD + n];   // broadcast load
        int cx = min((int)(pkx >> 24), BUCKET8);
        wfix += pkx & 0xFFFFFFu;
        if (lane >= pref && lane < pref + cx) { xsel = xx; xslot = lane - pref; }
        pref += cx;
    }
    int cnt = min(pref, 64);
    float di = rsqrtf((float)wfix * (1.0f / FIX32) + 1.0f);
    float acc[8];
    #pragma unroll
    for (int q = 0; q < 8; q++) acc[q] = 0.f;
    if (slot == 0) {
        float4 hv = xwh[n * 8 + c8];
        const __half2* h2 = reinterpret_cast<const __half2*>(&hv);
        #pragma unroll
        for (int q = 0; q < 4; q++) {
            float2 f = __half22float2(h2[q]);
            acc[2 * q]     = f.x;
            acc[2 * q + 1] = f.y;
        }
    }
    // fetch this lane's record (concatenated per-XCD lists, lane < cnt)
    int rv = 0; float wv = 0.f;
    if (xsel >= 0 && lane < cnt) {
        unsigned int rec = ren8[((size_t)xsel * N_NODES + n) * BUCKET8 + xslot];
        rv = (int)(rec & 0xFFFFu);
        __half_raw hr; hr.x = (unsigned short)(rec >> 16);
        wv = __half2float(__half(hr));
    }
    int G = (cnt + 7) >> 3;
    int g = 0;
    for (; g + 2 <= G; g += 2) {      // 16 independent gathers in flight
        int src0 = g * 8 + slot, src1 = src0 + 8;
        int   ra = __shfl(rv, src0);  float wa = __shfl(wv, src0);
        int   rb = __shfl(rv, src1);  float wb = __shfl(wv, src1);
        float4 ha = xwh[ra * 8 + c8];
        float4 hb = xwh[rb * 8 + c8];
        const __half2* h2a = reinterpret_cast<const __half2*>(&ha);
        const __half2* h2b = reinterpret_cast<const __half2*>(&hb);
        #pragma unroll
        for (int q = 0; q < 4; q++) {
            float2 fa = __half22float2(h2a[q]);
            float2 fb = __half22float2(h2b[q]);
            acc[2 * q]     += wa * fa.x + wb * fb.x;
            acc[2 * q + 1] += wa * fa.y + wb * fb.y;
        }
    }
    if (g < G) {
        int src = g * 8 + slot;
        int r = __shfl(rv, src);      // inactive slots: wv=0 -> no-op FMA
        float ww = __shfl(wv, src);
        float4 hv = xwh[r * 8 + c8];
        const __half2* h2 = reinterpret_cast<const __half2*>(&hv);
        #pragma unroll
        for (int q = 0; q < 4; q++) {
            float2 f = __half22float2(h2[q]);
            acc[2 * q]     += ww * f.x;
            acc[2 * q + 1] += ww * f.y;
        }
    }
    // reduce partial sums across the 8 slots (lane bits 3,4,5)
    #pragma unroll
    for (int q = 0; q < 8; q++) {
        acc[q] += __shfl_xor(acc[q], 8);
        acc[q] += __shfl_xor(acc[q], 16);
        acc[q] += __shfl_xor(acc[q], 32);
    }
    float pv = 0.f;
    #pragma unroll
    for (int q = 0; q < 8; q++)
        pv += fmaxf(di * acc[q], 0.f) * linW[c8 * 8 + q];
    pv += __shfl_xor(pv, 1); pv += __shfl_xor(pv, 2); pv += __shfl_xor(pv, 4);
    if (lane == 0) out[n] = pv + linb[0];
}

extern "C" void kernel_launch(void* const* d_in, const int* in_sizes, int n_in,
                              void* d_out, int out_size, void* d_ws, size_t ws_size,
                              hipStream_t stream) {
    const float* x     = (const float*)d_in[0];
    const int*   ei    = (const int*)d_in[1];
    const float* ew    = (const float*)d_in[2];
    const float* p     = (const float*)d_in[3];
    const float* initW = (const float*)d_in[4];
    const float* Wih   = (const float*)d_in[5];
    const float* Whh   = (const float*)d_in[6];
    const float* bih   = (const float*)d_in[7];
    const float* bhh   = (const float*)d_in[8];
    const float* linW  = (const float*)d_in[9];
    const float* linb  = (const float*)d_in[10];
    float* out = (float*)d_out;

    char* w = (char*)d_ws;
    unsigned int* packed8 = (unsigned int*)w; w += 4ull * NXCD * NPAD;              // 1.6 MB
    unsigned int* ren8 = (unsigned int*)w;    w += 4ull * NXCD * N_NODES * BUCKET8; // 38.4 MB
    __half* xwh    = (__half*)w;   w += 2ull * (size_t)N_NODES * DIM;               // 6.4 MB
    float* cand_val= (float*)w;    w += 4ull * 8192;
    int*   cand_idx= (int*)w;      w += 4ull * 8192;
    float* W       = (float*)w;    w += 4ull * 4096;

    // zero the 8 per-XCD counter copies (capture-legal memset node)
    hipMemsetAsync(packed8, 0, 4ull * NXCD * NPAD, stream);
    score_topk_edge_kernel<<<NB_EDGE, 512, 0, stream>>>(
        x, p, cand_val, cand_idx, ei, ew, packed8, ren8);
    topk_gru_kernel<<<1, 1024, 0, stream>>>(
        cand_val, cand_idx, x, initW, Wih, Whh, bih, bhh, W);
    xw_kernel<<<XW_BLOCKS, 256, 0, stream>>>(x, W, packed8, xwh);
    gather_head_kernel<<<(N_NODES * 64 + 255) / 256, 256, 0, stream>>>(
        packed8, ren8, (const float4*)xwh, linW, linb, out);
}

// Round 24
// 202.646 us; speedup vs baseline: 2.0461x; 1.7623x over previous
//
#include <hip/hip_runtime.h>
#include <hip/hip_fp16.h>
#include <cmath>

#define N_NODES 50000
#define NPAD 50016           // per-XCD packed stride; index N_NODES = dummy slot for OOB lanes
#define DIM 64
#define E_EDGES 800000
#define FIX32 65536.0f       // 2^16 fixed-point scale for deg (24-bit field, max 256)
#define NB_A 98              // score/sort blocks: 98 * 512 = 50176 >= 50000
#define NB_EDGE 391          // edge blocks: 391*512*4 = 800768 >= 800000 (4 edges/thread)
#define ESTRIDE (NB_EDGE * 512)
#define NRUNS 98             // sorted runs of 64 entering phase B
#define NXCD 8               // MI355X: 8 XCDs, per-XCD L2 (non-coherent)
#define BUCKET8 24           // per-(xcd,node) bucket capacity; deg ~Poisson(16) total
#define XW_BLOCKS 782        // ceil(50000 / 64)

// LEDGER (r10-r39). Edge atomic wall: shared+sc1=53; per-XCD sc0=50; 4x-outstanding=48.7;
// 32B-padded=flat (same-line serialization REFUTED) -> wall = random line-op service
// (~16G/s) across packed8+ren8. FUSION POST-MORTEMS: r20 coop-tail = 267us (23% occ,
// TLP-starved); r21 single-block topk+GRU = 189us (0.14% occ, 1-CU latency wall on
// stride-256B weight reads). BUDGET MODEL (confirmed x3): total = kernels + ~95-100us
// harness-fixed overhead (invariant to dispatch count). r9 config: edge 49 + tail ~55
// + fixed ~100 = 203.7. THIS ROUND (r37, resubmitted r38/r39 — infra timeouts): exact
// r9-verified source (best known). Next lever: ren8 scattered-store path isolation.

// XCD id of the executing wave (HW-verified on gfx950: s_getreg HW_REG_XCC_ID, m09)
__device__ __forceinline__ int xcc_id() {
    int x;
    asm volatile("s_getreg_b32 %0, hwreg(HW_REG_XCC_ID)" : "=s"(x));
    return x & 7;
}

// ======== wave-register bitonic helpers (comparator: val desc, idx asc) ========
__device__ __forceinline__ void wave_sort64(float& v, int& idx, int lane) {
    #pragma unroll
    for (int k = 2; k <= 64; k <<= 1) {
        #pragma unroll
        for (int j = k >> 1; j > 0; j >>= 1) {
            float ov = __shfl_xor(v, j);
            int   oi = __shfl_xor(idx, j);
            bool lower = ((lane & j) == 0);
            bool up    = ((lane & k) == 0);
            bool mine_prec = (v > ov) || (v == ov && idx < oi);
            bool keep = up ? (lower == mine_prec) : (lower != mine_prec);
            if (!keep) { v = ov; idx = oi; }
        }
    }
}

// A (desc, in regs) merged with B (bv/bi must hold B[63-lane]); result: top-64 desc
__device__ __forceinline__ void wave_merge_top64(float& v, int& idx,
                                                 float bv, int bi, int lane) {
    bool a_prec = (v > bv) || (v == bv && idx < bi);
    if (!a_prec) { v = bv; idx = bi; }
    #pragma unroll
    for (int j = 32; j > 0; j >>= 1) {
        float ov = __shfl_xor(v, j);
        int   oi = __shfl_xor(idx, j);
        bool lower = ((lane & j) == 0);
        bool mine_prec = (v > ov) || (v == ov && idx < oi);
        bool keep = (lower == mine_prec);   // up = true (full-width merge)
        if (!keep) { v = ov; idx = oi; }
    }
}

// ------ fused: score + top-k phase A (blocks<98) + batched edge pass (all blocks) ------
// Exact r6-measured config: 4 edges/thread, 4 L2-local RMWs in flight.
__global__ __launch_bounds__(512) void score_topk_edge_kernel(
    const float* __restrict__ x, const float* __restrict__ p,
    float* __restrict__ cand_val, int* __restrict__ cand_idx,
    const int* __restrict__ ei, const float* __restrict__ ew,
    unsigned int* __restrict__ packed8, unsigned int* __restrict__ ren8) {
    __shared__ float sv[512];
    __shared__ int   si[512];
    int t = threadIdx.x, lane = t & 63, wvid = t >> 6;
    if (blockIdx.x < NB_A) {
        int g = blockIdx.x * 512 + t;
        float v; int idx;
        if (g < N_NODES) {
            const float4* x4 = (const float4*)(x + (size_t)g * DIM);
            const float4* p4 = (const float4*)p;
            float dot = 0.f, pn = 0.f;
            #pragma unroll
            for (int k = 0; k < 16; k++) {
                float4 xv = x4[k], pv = p4[k];
                dot += xv.x * pv.x + xv.y * pv.y + xv.z * pv.z + xv.w * pv.w;
                pn  += pv.x * pv.x + pv.y * pv.y + pv.z * pv.z + pv.w * pv.w;
            }
            v = dot / sqrtf(pn);
            idx = g;
        } else { v = -INFINITY; idx = 0x7fffffff; }
        wave_sort64(v, idx, lane);
        sv[t] = v; si[t] = idx;
        __syncthreads();
        if (wvid == 0) {
            #pragma unroll
            for (int r = 1; r < 8; r++)
                wave_merge_top64(v, idx, sv[r * 64 + 63 - lane], si[r * 64 + 63 - lane], lane);
            cand_val[blockIdx.x * 64 + lane] = v;
            cand_idx[blockIdx.x * 64 + lane] = idx;
        }
    }
    // ---- batched edge pass: 4 edges/thread, 4 L2-local RMWs in flight ----
    int xcc = xcc_id();
    unsigned int* mypk  = packed8 + (size_t)xcc * NPAD;
    unsigned int* myren = ren8 + (size_t)xcc * N_NODES * BUCKET8;
    int e0 = blockIdx.x * 512 + t;       // 0 .. ESTRIDE-1
    int   rr[4]; int cc[4]; float wwv[4]; bool valid[4];
    #pragma unroll
    for (int k = 0; k < 4; k++) {
        int e = e0 + k * ESTRIDE;
        bool vld = (e < E_EDGES);
        int ie = vld ? e : 0;
        rr[k]  = ei[ie];
        cc[k]  = vld ? ei[E_EDGES + ie] : N_NODES;   // dummy slot for OOB
        wwv[k] = ew[ie];
        valid[k] = vld;
    }
    unsigned int q[4];
    unsigned int* ap[4];
    #pragma unroll
    for (int k = 0; k < 4; k++) {
        q[k] = valid[k] ? ((1u << 24) | (unsigned int)(wwv[k] * FIX32)) : 0u;
        ap[k] = &mypk[cc[k]];
    }
    unsigned int o0, o1, o2, o3;
    asm volatile(
        "global_atomic_add %0, %4, %8, off sc0\n\t"
        "global_atomic_add %1, %5, %9, off sc0\n\t"
        "global_atomic_add %2, %6, %10, off sc0\n\t"
        "global_atomic_add %3, %7, %11, off sc0\n\t"
        "s_waitcnt vmcnt(0)"
        : "=&v"(o0), "=&v"(o1), "=&v"(o2), "=&v"(o3)
        : "v"(ap[0]), "v"(ap[1]), "v"(ap[2]), "v"(ap[3]),
          "v"(q[0]), "v"(q[1]), "v"(q[2]), "v"(q[3])
        : "memory");
    unsigned int oo[4] = {o0, o1, o2, o3};
    #pragma unroll
    for (int k = 0; k < 4; k++) {
        unsigned int pos = oo[k] >> 24;
        if (valid[k] && pos < BUCKET8) {
            __half hw = __float2half(wwv[k]);
            unsigned int rec = ((unsigned int)__half_as_ushort(hw) << 16) | (unsigned int)rr[k];
            myren[(size_t)cc[k] * BUCKET8 + pos] = rec;
        }
    }
}

// ---------------- top-k phase B: merge 98 runs, build x_tilde (1 block) ----------------
__global__ __launch_bounds__(1024) void topk_b_kernel(
    const float* __restrict__ cand_val, const int* __restrict__ cand_idx,
    const float* __restrict__ x, float* __restrict__ x_tilde) {
    __shared__ float rsv[16 * 64];
    __shared__ int   rsi[16 * 64];
    __shared__ float tval[64];
    __shared__ int   perm[64];
    int t = threadIdx.x, lane = t & 63, wv = t >> 6;
    int r0 = wv * 8;
    float v; int idx;
    if (r0 < NRUNS) { v = cand_val[r0 * 64 + lane]; idx = cand_idx[r0 * 64 + lane]; }
    else            { v = -INFINITY; idx = 0x7fffffff; }
    for (int r = r0 + 1; r < r0 + 8 && r < NRUNS; r++)
        wave_merge_top64(v, idx, cand_val[r * 64 + 63 - lane],
                         cand_idx[r * 64 + 63 - lane], lane);
    rsv[wv * 64 + lane] = v; rsi[wv * 64 + lane] = idx;
    __syncthreads();
    if (wv == 0) {
        v = rsv[lane]; idx = rsi[lane];
        for (int r = 1; r < 16; r++)
            wave_merge_top64(v, idx, rsv[r * 64 + 63 - lane],
                             rsi[r * 64 + 63 - lane], lane);
        tval[lane] = tanhf(v);
        perm[lane] = idx;
    }
    __syncthreads();
    for (int i = t; i < 4096; i += 1024) {
        int j = i >> 6, kk = i & 63;
        x_tilde[i] = x[perm[j] * DIM + kk] * tval[j];
    }
}

// ---------------- GRU step (16 blocks x 256, 4 rows per block) ----------------
__global__ __launch_bounds__(256) void gru_kernel(
    const float* __restrict__ xt, const float* __restrict__ initW,
    const float* __restrict__ Wih, const float* __restrict__ Whh,
    const float* __restrict__ bih, const float* __restrict__ bhh,
    float* __restrict__ Wout) {
    __shared__ float xrow_s[256], hrow_s[256];
    int t = threadIdx.x;
    int i = blockIdx.x * 4 + (t >> 6);   // row 0..63
    int j = t & 63;
    int li = (t >> 6) * 64 + j;
    xrow_s[li] = xt[i * 64 + j];
    hrow_s[li] = initW[i * 64 + j];
    __syncthreads();
    int lb = (t >> 6) * 64;
    float gi_r = bih[j], gi_z = bih[j + 64], gi_n = bih[j + 128];
    float gh_r = bhh[j], gh_z = bhh[j + 64], gh_n = bhh[j + 128];
    for (int k = 0; k < 64; k++) {
        float xv = xrow_s[lb + k], hv = hrow_s[lb + k];
        gi_r += xv * Wih[j * 64 + k];
        gi_z += xv * Wih[(j + 64) * 64 + k];
        gi_n += xv * Wih[(j + 128) * 64 + k];
        gh_r += hv * Whh[j * 64 + k];
        gh_z += hv * Whh[(j + 64) * 64 + k];
        gh_n += hv * Whh[(j + 128) * 64 + k];
    }
    float r = 1.f / (1.f + expf(-(gi_r + gh_r)));
    float z = 1.f / (1.f + expf(-(gi_z + gh_z)));
    float nn = tanhf(gi_n + r * gh_n);
    Wout[i * 64 + j] = (1.f - z) * nn + z * hrow_s[lb + j];
}

// ---------------- xw = dinv[r] * (x @ W), output fp16 (pre-scaled rows) ----------------
__global__ __launch_bounds__(256) void xw_kernel(
    const float* __restrict__ x, const float* __restrict__ W,
    const unsigned int* __restrict__ packed8, __half* __restrict__ xwh) {
    __shared__ float Wl[64 * 64];
    __shared__ float Xl[64 * 64];
    __shared__ float dinv_s[64];
    int t = threadIdx.x;
    int r0 = blockIdx.x * 64;
    if (t < 64) {
        int r = r0 + t;
        unsigned int s = 0;
        if (r < N_NODES) {
            #pragma unroll
            for (int xx = 0; xx < NXCD; xx++)
                s += packed8[(size_t)xx * NPAD + r] & 0xFFFFFFu;
        }
        dinv_s[t] = rsqrtf((float)s * (1.0f / FIX32) + 1.0f);
    }
    for (int i = t; i < 4096; i += 256) Wl[i] = W[i];
    for (int i = t; i < 4096; i += 256) {
        int r = r0 + (i >> 6);
        Xl[i] = (r < N_NODES) ? x[r0 * 64 + i] : 0.f;
    }
    __syncthreads();
    int j = t & 63, ty = t >> 6;
    float acc[16];
    #pragma unroll
    for (int rr = 0; rr < 16; rr++) acc[rr] = 0.f;
    for (int k = 0; k < 64; k++) {
        float wvv = Wl[k * 64 + j];
        #pragma unroll
        for (int rr = 0; rr < 16; rr++)
            acc[rr] += Xl[(ty * 16 + rr) * 64 + k] * wvv;
    }
    #pragma unroll
    for (int rr = 0; rr < 16; rr++) {
        int r = r0 + ty * 16 + rr;
        if (r < N_NODES)
            xwh[r * DIM + j] = __float2half(acc[rr] * dinv_s[ty * 16 + rr]);
    }
}

// ------- gather + fused head: wave per node, walks 8 per-XCD bucket lists -------
// agg[n] = dinv[n] * (xwh[n] + sum_e w_e * xwh[row_e]);  out = relu(agg) @ linW + b
__global__ __launch_bounds__(256) void gather_head_kernel(
    const unsigned int* __restrict__ packed8, const unsigned int* __restrict__ ren8,
    const float4* __restrict__ xwh,   // 8 float4 (= 64 halves) per row
    const float* __restrict__ linW, const float* __restrict__ linb,
    float* __restrict__ out) {
    int gid = blockIdx.x * blockDim.x + threadIdx.x;
    int n = gid >> 6, lane = gid & 63;
    if (n >= N_NODES) return;
    int c8 = lane & 7;        // columns c8*8 .. c8*8+7
    int slot = lane >> 3;     // 8 row-slots per wave
    // per-XCD counts -> lane's (list, slot) assignment + total weighted degree
    int xsel = -1, xslot = 0, pref = 0;
    unsigned int wfix = 0;
    #pragma unroll
    for (int xx = 0; xx < NXCD; xx++) {
        unsigned int pkx = packed8[(size_t)xx * NPAD + n];   // broadcast load
        int cx = min((int)(pkx >> 24), BUCKET8);
        wfix += pkx & 0xFFFFFFu;
        if (lane >= pref && lane < pref + cx) { xsel = xx; xslot = lane - pref; }
        pref += cx;
    }
    int cnt = min(pref, 64);
    float di = rsqrtf((float)wfix * (1.0f / FIX32) + 1.0f);
    float acc[8];
    #pragma unroll
    for (int q = 0; q < 8; q++) acc[q] = 0.f;
    if (slot == 0) {
        float4 hv = xwh[n * 8 + c8];
        const __half2* h2 = reinterpret_cast<const __half2*>(&hv);
        #pragma unroll
        for (int q = 0; q < 4; q++) {
            float2 f = __half22float2(h2[q]);
            acc[2 * q]     = f.x;
            acc[2 * q + 1] = f.y;
        }
    }
    // fetch this lane's record (concatenated per-XCD lists, lane < cnt)
    int rv = 0; float wv = 0.f;
    if (xsel >= 0 && lane < cnt) {
        unsigned int rec = ren8[((size_t)xsel * N_NODES + n) * BUCKET8 + xslot];
        rv = (int)(rec & 0xFFFFu);
        __half_raw hr; hr.x = (unsigned short)(rec >> 16);
        wv = __half2float(__half(hr));
    }
    int G = (cnt + 7) >> 3;
    int g = 0;
    for (; g + 2 <= G; g += 2) {      // 16 independent gathers in flight
        int src0 = g * 8 + slot, src1 = src0 + 8;
        int   ra = __shfl(rv, src0);  float wa = __shfl(wv, src0);
        int   rb = __shfl(rv, src1);  float wb = __shfl(wv, src1);
        float4 ha = xwh[ra * 8 + c8];
        float4 hb = xwh[rb * 8 + c8];
        const __half2* h2a = reinterpret_cast<const __half2*>(&ha);
        const __half2* h2b = reinterpret_cast<const __half2*>(&hb);
        #pragma unroll
        for (int q = 0; q < 4; q++) {
            float2 fa = __half22float2(h2a[q]);
            float2 fb = __half22float2(h2b[q]);
            acc[2 * q]     += wa * fa.x + wb * fb.x;
            acc[2 * q + 1] += wa * fa.y + wb * fb.y;
        }
    }
    if (g < G) {
        int src = g * 8 + slot;
        int r = __shfl(rv, src);      // inactive slots: wv=0 -> no-op FMA
        float ww = __shfl(wv, src);
        float4 hv = xwh[r * 8 + c8];
        const __half2* h2 = reinterpret_cast<const __half2*>(&hv);
        #pragma unroll
        for (int q = 0; q < 4; q++) {
            float2 f = __half22float2(h2[q]);
            acc[2 * q]     += ww * f.x;
            acc[2 * q + 1] += ww * f.y;
        }
    }
    // reduce partial sums across the 8 slots (lane bits 3,4,5)
    #pragma unroll
    for (int q = 0; q < 8; q++) {
        acc[q] += __shfl_xor(acc[q], 8);
        acc[q] += __shfl_xor(acc[q], 16);
        acc[q] += __shfl_xor(acc[q], 32);
    }
    float pv = 0.f;
    #pragma unroll
    for (int q = 0; q < 8; q++)
        pv += fmaxf(di * acc[q], 0.f) * linW[c8 * 8 + q];
    pv += __shfl_xor(pv, 1); pv += __shfl_xor(pv, 2); pv += __shfl_xor(pv, 4);
    if (lane == 0) out[n] = pv + linb[0];
}

extern "C" void kernel_launch(void* const* d_in, const int* in_sizes, int n_in,
                              void* d_out, int out_size, void* d_ws, size_t ws_size,
                              hipStream_t stream) {
    const float* x     = (const float*)d_in[0];
    const int*   ei    = (const int*)d_in[1];
    const float* ew    = (const float*)d_in[2];
    const float* p     = (const float*)d_in[3];
    const float* initW = (const float*)d_in[4];
    const float* Wih   = (const float*)d_in[5];
    const float* Whh   = (const float*)d_in[6];
    const float* bih   = (const float*)d_in[7];
    const float* bhh   = (const float*)d_in[8];
    const float* linW  = (const float*)d_in[9];
    const float* linb  = (const float*)d_in[10];
    float* out = (float*)d_out;

    char* w = (char*)d_ws;
    unsigned int* packed8 = (unsigned int*)w; w += 4ull * NXCD * NPAD;              // 1.6 MB
    unsigned int* ren8 = (unsigned int*)w;    w += 4ull * NXCD * N_NODES * BUCKET8; // 38.4 MB
    __half* xwh    = (__half*)w;   w += 2ull * (size_t)N_NODES * DIM;               // 6.4 MB
    float* cand_val= (float*)w;    w += 4ull * 8192;
    int*   cand_idx= (int*)w;      w += 4ull * 8192;
    float* x_tilde = (float*)w;    w += 4ull * 4096;
    float* W       = (float*)w;    w += 4ull * 4096;

    // zero the 8 per-XCD counter copies (capture-legal memset node)
    hipMemsetAsync(packed8, 0, 4ull * NXCD * NPAD, stream);
    score_topk_edge_kernel<<<NB_EDGE, 512, 0, stream>>>(
        x, p, cand_val, cand_idx, ei, ew, packed8, ren8);
    topk_b_kernel<<<1, 1024, 0, stream>>>(cand_val, cand_idx, x, x_tilde);
    gru_kernel<<<16, 256, 0, stream>>>(x_tilde, initW, Wih, Whh, bih, bhh, W);
    xw_kernel<<<XW_BLOCKS, 256, 0, stream>>>(x, W, packed8, xwh);
    gather_head_kernel<<<(N_NODES * 64 + 255) / 256, 256, 0, stream>>>(
        packed8, ren8, (const float4*)xwh, linW, linb, out);
}